// Round 1
// 258.281 us; speedup vs baseline: 1.1109x; 1.1109x over previous
//
#include <hip/hip_runtime.h>

// LSTMNextToken: embed-gather -> 2x LSTM -> LayerNorm -> tied-embedding head.
// I/O dtypes: float tensors are float32; x is int32. Internals f16/bf16 MFMA.
//
// R6 pipeline:
//  k_ew    : EW[v][g] = embed[v]@Wih0^T + bih0 + bhh0       (433x480 f32, L2-resident)
//  k_prep2 : embP bf16 [448][128] zero-padded; b1s = bih1+bhh1 (f32)
//  k_rec0  : MFMA LSTM layer 0 (src = EW gather, prefetched) -> hb0 f16 t-major
//  k_rec1  : MFMA LSTM layer 1 + shuffle-LayerNorm + FUSED tied-embedding head
//            (embP staged in LDS; per-step 16x448 logits via bf16 MFMA -> d_out)
// R5->R6: k_head dispatch eliminated. Head MFMA+stores execute in k_rec1's
// latency bubbles (rec1 was latency-bound: VALUBusy 33%, MfmaUtil 8%); h1n
// global round-trip (33 MB) removed. LN result goes to LDS hnL instead of
// global. LDS: 30976(gLs)+4352(hLh)+4352(hnL)+121856(embL) = 161536 B of
// 163840 cap. Watch VGPR_Count for spills (head adds ~36 transients).

#define VSZ 433
#define DIM 120
#define BSZ 4096
#define SEQ 16
#define H4  480
#define MTOT (BSZ*SEQ)   // 65536
#define KP  128          // padded K for MFMA
#define NPAD 448         // padded vocab for head
#define NT_HEAD (NPAD/16) // 28 head n-tiles
#define TB  16           // batch rows per rec block
#define GP  484          // gates LDS row pad (484%32=4 -> 2-way banks = free)
#define HP  136          // h-state LDS row pad in f16/bf16 (272 B = 16*17: b128-aligned, 2-way banks)

typedef unsigned int   u32;
typedef unsigned short u16;
typedef __attribute__((ext_vector_type(8))) short    v8bf; // 8 x bf16
typedef __attribute__((ext_vector_type(8))) _Float16 v8h;  // 8 x f16
typedef __attribute__((ext_vector_type(4))) float    v4f;  // MFMA acc

__device__ __forceinline__ float bf2f(u16 u){ union{u32 i;float f;}z; z.i=((u32)u)<<16; return z.f; }
__device__ __forceinline__ u16 f2bf(float f){ // RNE
  union{float f;u32 u;}z; z.f=f;
  u32 u = z.u + 0x7fffu + ((z.u>>16)&1u);
  return (u16)(u>>16);
}
__device__ __forceinline__ u32 packh2(float a, float b){
  union{_Float16 h[2]; u32 u;} z;
  z.h[0] = (_Float16)a; z.h[1] = (_Float16)b;
  return z.u;
}

// ---------------- workspace layout (bytes, 256-aligned) ----------------
#define EW_OFF   0u          // 433*480*4   = 831360
#define B1S_OFF  831488u     // 480*4       = 1920
#define EMBP_OFF 833408u     // 448*128*2   = 114688
#define HB0_OFF  948096u     // 65536*128*2 = 16777216  (f16, t-major)

// ---------------- k_ew ----------------
__global__ __launch_bounds__(512) void k_ew(const float* __restrict__ embed,
                                            const float* __restrict__ Wih0,
                                            const float* __restrict__ bih0,
                                            const float* __restrict__ bhh0,
                                            float* __restrict__ EW)
{
  __shared__ float e[DIM];
  const int v = blockIdx.x, tid = threadIdx.x;
  if (tid < DIM) e[tid] = embed[v*DIM + tid];
  __syncthreads();
  if (tid < H4) {
    float acc = bih0[tid] + bhh0[tid];
    #pragma unroll
    for (int k0 = 0; k0 < DIM; k0 += 4) {
      float4 w = *(const float4*)(Wih0 + tid*DIM + k0);
      acc = fmaf(e[k0+0], w.x, acc);
      acc = fmaf(e[k0+1], w.y, acc);
      acc = fmaf(e[k0+2], w.z, acc);
      acc = fmaf(e[k0+3], w.w, acc);
    }
    EW[v*H4 + tid] = acc;
  }
}

// ---------------- k_prep2: embP bf16 padded + b1s ----------------
__global__ __launch_bounds__(256) void k_prep2(const float* __restrict__ embed,
                                               const float* __restrict__ bih1,
                                               const float* __restrict__ bhh1,
                                               u16* __restrict__ embP,
                                               float* __restrict__ b1s)
{
  const int idx = blockIdx.x*256 + threadIdx.x;
  if (idx < NPAD*KP) {
    int n = idx >> 7, k = idx & 127;
    embP[idx] = (n < VSZ && k < DIM) ? f2bf(embed[n*DIM + k]) : (u16)0;
  } else if (idx < NPAD*KP + H4) {
    int g = idx - NPAD*KP;
    b1s[g] = bih1[g] + bhh1[g];
  }
}

// ---------------- k_rec0: MFMA LSTM layer 0 ----------------
// 512 thr = 8 waves. MFMA: wave owns n-tiles wave*4..+3 (>=30 dead), Whh0
// resident f16 B-frags, src = EW gather prefetched 1 step. Phase B: wave owns
// rows {2w,2w+1}, lane l<60 owns dims {2l,2l+1} (b64 gate reads, b32 stores;
// lanes 60-63 write the hb0 pad cols). 2 barriers/step.
__global__ __launch_bounds__(512) void k_rec0(const float* __restrict__ Whh,
                                              const float* __restrict__ EW,
                                              const int* __restrict__ x,
                                              _Float16* __restrict__ hb0)
{
  __shared__ float gLs[TB][GP];                    // 30976 B
  __shared__ __align__(16) _Float16 hLh[TB][HP];   //  4352 B
  __shared__ int xL[TB*SEQ];                       //  1024 B

  const int tid  = threadIdx.x;
  const int wave = tid >> 6, lane = tid & 63;
  const int cl   = lane & 15, quad = lane >> 4;
  const int b0   = blockIdx.x * TB;

  for (int i = tid; i < TB*SEQ; i += 512) xL[i] = x[b0*SEQ + i];
  for (int i = tid; i < TB*HP; i += 512) (&hLh[0][0])[i] = (_Float16)0.f;
  __syncthreads();

  v8h Bf[4][4];
  #pragma unroll
  for (int i = 0; i < 4; ++i) {
    const int nt = wave*4 + i;
    const bool vld = (nt < 30);
    const int n = vld ? nt*16 + cl : 0;
    #pragma unroll
    for (int kt = 0; kt < 4; ++kt) {
      const int k0 = kt*32 + quad*8;
      v8h f = {0,0,0,0,0,0,0,0};
      if (vld && k0 < DIM) {
        float4 q0 = *(const float4*)(Whh + n*DIM + k0);
        float4 q1 = *(const float4*)(Whh + n*DIM + k0 + 4);
        f[0]=(_Float16)q0.x; f[1]=(_Float16)q0.y; f[2]=(_Float16)q0.z; f[3]=(_Float16)q0.w;
        f[4]=(_Float16)q1.x; f[5]=(_Float16)q1.y; f[6]=(_Float16)q1.z; f[7]=(_Float16)q1.w;
      }
      Bf[i][kt] = f;
    }
  }

  float srcv[4][4];
  auto load_src = [&](int t) {
    #pragma unroll
    for (int i = 0; i < 4; ++i) {
      const int nt = wave*4 + i;
      if (nt < 30) {
        const int n = nt*16 + cl;
        #pragma unroll
        for (int r = 0; r < 4; ++r)
          srcv[i][r] = EW[(size_t)xL[(quad*4 + r)*SEQ + t]*H4 + n];
      }
    }
  };
  load_src(0);

  // phase-B mapping: wave owns rows {2w,2w+1}; lane l<60 owns dims {2l,2l+1}
  const int prow = wave*2;
  const bool act = lane < 60;
  const int d0   = lane*2;
  float C[2][2] = {{0.f,0.f},{0.f,0.f}};

  for (int t = 0; t < SEQ; ++t) {
    __syncthreads();   // hLh (prev phase B / init) visible
    v8h Af[4];
    #pragma unroll
    for (int kt = 0; kt < 4; ++kt)
      Af[kt] = *(const v8h*)&hLh[cl][kt*32 + quad*8];
    v4f acc[4];
    #pragma unroll
    for (int i = 0; i < 4; ++i) {
      acc[i][0]=srcv[i][0]; acc[i][1]=srcv[i][1];
      acc[i][2]=srcv[i][2]; acc[i][3]=srcv[i][3];
    }
    #pragma unroll
    for (int i = 0; i < 4; ++i)
      if (wave*4 + i < 30) {
        #pragma unroll
        for (int kt = 0; kt < 4; ++kt)
          acc[i] = __builtin_amdgcn_mfma_f32_16x16x32_f16(Af[kt], Bf[i][kt], acc[i], 0, 0, 0);
      }
    if (t + 1 < SEQ) load_src(t + 1);
    #pragma unroll
    for (int i = 0; i < 4; ++i) {
      const int nt = wave*4 + i;
      if (nt < 30) {
        #pragma unroll
        for (int r = 0; r < 4; ++r)
          gLs[quad*4 + r][nt*16 + cl] = acc[i][r];
      }
    }
    __syncthreads();   // gates visible
    #pragma unroll
    for (int rr = 0; rr < 2; ++rr) {
      const int row = prow + rr;
      if (act) {
        const float2 gi = *(const float2*)&gLs[row][d0      ];
        const float2 gf = *(const float2*)&gLs[row][d0 + 120];
        const float2 gg = *(const float2*)&gLs[row][d0 + 240];
        const float2 go = *(const float2*)&gLs[row][d0 + 360];
        float h2[2];
        #pragma unroll
        for (int k = 0; k < 2; ++k) {
          const float vi = k ? gi.y : gi.x, vf = k ? gf.y : gf.x;
          const float vg = k ? gg.y : gg.x, vo = k ? go.y : go.x;
          const float si = 1.f / (1.f + __expf(-vi));
          const float sf = 1.f / (1.f + __expf(-vf));
          const float tg = 1.f - 2.f / (__expf(2.f*vg) + 1.f);
          const float so = 1.f / (1.f + __expf(-vo));
          const float c  = sf * C[rr][k] + si * tg;
          C[rr][k] = c;
          const float tc = 1.f - 2.f / (__expf(2.f*c) + 1.f);
          h2[k] = so * tc;
        }
        *(u32*)&hLh[row][d0] = packh2(h2[0], h2[1]);
        *(u32*)&hb0[((size_t)t*BSZ + b0 + row)*KP + d0] = packh2(h2[0], h2[1]);
      } else {
        // lanes 60..63: zero hb0 pad cols 120..127 (2 per lane)
        *(u32*)&hb0[((size_t)t*BSZ + b0 + row)*KP + 120 + 2*(lane - 60)] = 0u;
      }
    }
  }
}

// ---------------- k_rec1: LSTM layer 1 + shuffle-LN + fused head ----------------
// gates = b1s + hb0[t]@Wih1^T + h1@Whh1^T (resident f16 frags). A0 frags
// prefetched from global 1 step ahead. Phase B wave-owns-2-rows; LN mean/var
// via __shfl_xor tree; LN result -> LDS hnL (bf16). After the hLh barrier,
// the tied-embedding head for this step runs from LDS (embL staged once):
// logits[16 rows x 448] via 16 bf16 MFMA/wave, stores hide under the next
// step's recurrence latency. 2 barriers/step.
__global__ __launch_bounds__(512) void k_rec1(const float* __restrict__ Wih1,
                                              const float* __restrict__ Whh1,
                                              const float* __restrict__ b1s,
                                              const _Float16* __restrict__ hb0,
                                              const float* __restrict__ gamma,
                                              const float* __restrict__ beta,
                                              const u16* __restrict__ embP,
                                              float* __restrict__ out)
{
  __shared__ float gLs[TB][GP];                    //  30976 B
  __shared__ __align__(16) _Float16 hLh[TB][HP];   //   4352 B
  __shared__ __align__(16) u16 hnL[TB][HP];        //   4352 B (LN'd h, bf16)
  __shared__ __align__(16) u16 embL[NPAD][HP];     // 121856 B (tied embedding, bf16)

  const int tid  = threadIdx.x;
  const int wave = tid >> 6, lane = tid & 63;
  const int cl   = lane & 15, quad = lane >> 4;
  const int b0   = blockIdx.x * TB;

  for (int i = tid; i < TB*HP; i += 512) (&hLh[0][0])[i] = (_Float16)0.f;
  // stage embP [448][128] -> embL [448][HP] (16 B chunks; 14 iters/thread)
  for (int c = tid; c < NPAD*16; c += 512) {
    const int rw = c >> 4, c16 = c & 15;
    *(v8bf*)&embL[rw][c16*8] = *(const v8bf*)&embP[(size_t)rw*KP + c16*8];
  }

  v8h Bi[4][4], Bh[4][4];
  float bias[4];
  #pragma unroll
  for (int i = 0; i < 4; ++i) {
    const int nt = wave*4 + i;
    const bool vld = (nt < 30);
    const int n = vld ? nt*16 + cl : 0;
    bias[i] = vld ? b1s[n] : 0.f;
    #pragma unroll
    for (int kt = 0; kt < 4; ++kt) {
      const int k0 = kt*32 + quad*8;
      v8h fi = {0,0,0,0,0,0,0,0}, fh = {0,0,0,0,0,0,0,0};
      if (vld && k0 < DIM) {
        float4 q0 = *(const float4*)(Wih1 + n*DIM + k0);
        float4 q1 = *(const float4*)(Wih1 + n*DIM + k0 + 4);
        fi[0]=(_Float16)q0.x; fi[1]=(_Float16)q0.y; fi[2]=(_Float16)q0.z; fi[3]=(_Float16)q0.w;
        fi[4]=(_Float16)q1.x; fi[5]=(_Float16)q1.y; fi[6]=(_Float16)q1.z; fi[7]=(_Float16)q1.w;
        float4 p0 = *(const float4*)(Whh1 + n*DIM + k0);
        float4 p1 = *(const float4*)(Whh1 + n*DIM + k0 + 4);
        fh[0]=(_Float16)p0.x; fh[1]=(_Float16)p0.y; fh[2]=(_Float16)p0.z; fh[3]=(_Float16)p0.w;
        fh[4]=(_Float16)p1.x; fh[5]=(_Float16)p1.y; fh[6]=(_Float16)p1.z; fh[7]=(_Float16)p1.w;
      }
      Bi[i][kt] = fi;
      Bh[i][kt] = fh;
    }
  }

  // phase-B mapping
  const int prow = wave*2;
  const bool act = lane < 60;
  const int d0   = lane*2;
  float gmm[2] = {0.f, 0.f}, bta[2] = {0.f, 0.f};
  if (act) {
    gmm[0] = gamma[d0]; gmm[1] = gamma[d0+1];
    bta[0] = beta[d0];  bta[1] = beta[d0+1];
  }
  float C[2][2] = {{0.f,0.f},{0.f,0.f}};

  // A0 prefetch (t=0)
  v8h A0n[4];
  #pragma unroll
  for (int kt = 0; kt < 4; ++kt)
    A0n[kt] = *(const v8h*)&hb0[((size_t)0*BSZ + b0 + cl)*KP + kt*32 + quad*8];
  __syncthreads();

  for (int t = 0; t < SEQ; ++t) {
    v8h A0c[4], A1[4];
    #pragma unroll
    for (int kt = 0; kt < 4; ++kt) A0c[kt] = A0n[kt];
    #pragma unroll
    for (int kt = 0; kt < 4; ++kt)
      A1[kt] = *(const v8h*)&hLh[cl][kt*32 + quad*8];
    if (t + 1 < SEQ) {
      #pragma unroll
      for (int kt = 0; kt < 4; ++kt)
        A0n[kt] = *(const v8h*)&hb0[((size_t)(t+1)*BSZ + b0 + cl)*KP + kt*32 + quad*8];
    }
    v4f acc[4];
    #pragma unroll
    for (int i = 0; i < 4; ++i)
      acc[i] = (v4f){bias[i], bias[i], bias[i], bias[i]};
    #pragma unroll
    for (int i = 0; i < 4; ++i)
      if (wave*4 + i < 30) {
        #pragma unroll
        for (int kt = 0; kt < 4; ++kt) {
          acc[i] = __builtin_amdgcn_mfma_f32_16x16x32_f16(A0c[kt], Bi[i][kt], acc[i], 0, 0, 0);
          acc[i] = __builtin_amdgcn_mfma_f32_16x16x32_f16(A1[kt],  Bh[i][kt], acc[i], 0, 0, 0);
        }
      }
    #pragma unroll
    for (int i = 0; i < 4; ++i) {
      const int nt = wave*4 + i;
      if (nt < 30) {
        #pragma unroll
        for (int r = 0; r < 4; ++r)
          gLs[quad*4 + r][nt*16 + cl] = acc[i][r];
      }
    }
    __syncthreads();   // gates visible
    float h2[2][2] = {{0.f,0.f},{0.f,0.f}};
    float s1[2] = {0.f, 0.f}, s2[2] = {0.f, 0.f};
    #pragma unroll
    for (int rr = 0; rr < 2; ++rr) {
      const int row = prow + rr;
      if (act) {
        const float2 gi = *(const float2*)&gLs[row][d0      ];
        const float2 gf = *(const float2*)&gLs[row][d0 + 120];
        const float2 gg = *(const float2*)&gLs[row][d0 + 240];
        const float2 go = *(const float2*)&gLs[row][d0 + 360];
        #pragma unroll
        for (int k = 0; k < 2; ++k) {
          const float vi = k ? gi.y : gi.x, vf = k ? gf.y : gf.x;
          const float vg = k ? gg.y : gg.x, vo = k ? go.y : go.x;
          const float si = 1.f / (1.f + __expf(-vi));
          const float sf = 1.f / (1.f + __expf(-vf));
          const float tg = 1.f - 2.f / (__expf(2.f*vg) + 1.f);
          const float so = 1.f / (1.f + __expf(-vo));
          const float c  = sf * C[rr][k] + si * tg;
          C[rr][k] = c;
          const float tc = 1.f - 2.f / (__expf(2.f*c) + 1.f);
          const float h  = so * tc;
          h2[rr][k] = h;
          s1[rr] += h;
          s2[rr] = fmaf(h, h, s2[rr]);
        }
        *(u32*)&hLh[row][d0] = packh2(h2[rr][0], h2[rr][1]);
      }
    }
    // LN reduction across the wave (all 64 lanes participate; idle lanes add 0)
    #pragma unroll
    for (int m = 32; m >= 1; m >>= 1) {
      s1[0] += __shfl_xor(s1[0], m);
      s2[0] += __shfl_xor(s2[0], m);
      s1[1] += __shfl_xor(s1[1], m);
      s2[1] += __shfl_xor(s2[1], m);
    }
    #pragma unroll
    for (int rr = 0; rr < 2; ++rr) {
      const int row = prow + rr;
      const float mu = s1[rr] * (1.f/DIM);
      const float var = s2[rr] * (1.f/DIM) - mu*mu;
      const float rs = rsqrtf(var + 1e-5f);
      if (act) {
        const float v0 = fmaf((h2[rr][0] - mu)*rs, gmm[0], bta[0]);
        const float v1 = fmaf((h2[rr][1] - mu)*rs, gmm[1], bta[1]);
        *(u32*)&hnL[row][d0] = (u32)f2bf(v0) | ((u32)f2bf(v1) << 16);
      } else {
        *(u32*)&hnL[row][120 + 2*(lane - 60)] = 0u;   // zero pad cols
      }
    }
    __syncthreads();   // hLh + hnL stable

    // ---- fused tied-embedding head for step t (from LDS, stores fire&forget)
    {
      v8bf a[4];
      #pragma unroll
      for (int kt = 0; kt < 4; ++kt)
        a[kt] = *(const v8bf*)&hnL[cl][kt*32 + quad*8];
      #pragma unroll
      for (int j = 0; j < 4; ++j) {
        const int nt = wave + 8*j;            // waves 0-3: 4 tiles, 4-7: 3 tiles
        if (nt < NT_HEAD) {
          const int n = nt*16 + cl;
          v8bf bfr[4];
          #pragma unroll
          for (int kt = 0; kt < 4; ++kt)
            bfr[kt] = *(const v8bf*)&embL[n][kt*32 + quad*8];
          v4f hacc = {0.f, 0.f, 0.f, 0.f};
          #pragma unroll
          for (int kt = 0; kt < 4; ++kt)
            hacc = __builtin_amdgcn_mfma_f32_16x16x32_bf16(a[kt], bfr[kt], hacc, 0, 0, 0);
          if (n < VSZ) {
            #pragma unroll
            for (int r = 0; r < 4; ++r)
              out[((size_t)(b0 + quad*4 + r)*SEQ + t)*VSZ + n] = hacc[r];
          }
        }
      }
    }
  }
}

// ---------------- launch ----------------
extern "C" void kernel_launch(void* const* d_in, const int* in_sizes, int n_in,
                              void* d_out, int out_size, void* d_ws, size_t ws_size,
                              hipStream_t stream)
{
  (void)in_sizes; (void)n_in; (void)out_size; (void)ws_size;
  const int*   x     = (const int*)d_in[0];
  const float* embed = (const float*)d_in[1];
  const float* Wih0  = (const float*)d_in[2];
  const float* Whh0  = (const float*)d_in[3];
  const float* bih0  = (const float*)d_in[4];
  const float* bhh0  = (const float*)d_in[5];
  const float* Wih1  = (const float*)d_in[6];
  const float* Whh1  = (const float*)d_in[7];
  const float* bih1  = (const float*)d_in[8];
  const float* bhh1  = (const float*)d_in[9];
  const float* gamma = (const float*)d_in[10];
  const float* beta  = (const float*)d_in[11];

  char* ws = (char*)d_ws;
  float*     EW   = (float*)(ws + EW_OFF);
  float*     b1s  = (float*)(ws + B1S_OFF);
  u16*       embP = (u16*)(ws + EMBP_OFF);
  _Float16*  hb0  = (_Float16*)(ws + HB0_OFF);

  k_ew   <<<VSZ, 512, 0, stream>>>(embed, Wih0, bih0, bhh0, EW);
  k_prep2<<<226, 256, 0, stream>>>(embed, bih1, bhh1, embP, b1s);
  k_rec0 <<<BSZ/TB, 512, 0, stream>>>(Whh0, EW, x, hb0);
  k_rec1 <<<BSZ/TB, 512, 0, stream>>>(Wih1, Whh1, b1s, hb0, gamma, beta, embP, (float*)d_out);
}